// Round 6
// baseline (570.702 us; speedup 1.0000x reference)
//
#include <hip/hip_runtime.h>

#define HH 512
#define WW 512
#define BB 2
#define CKXY 0.3125f   /* COMPACT / sqrt(H*W/NSUP) = 10/32 */
#define HW (HH*WW)

// --------------------------------------------------- direct conv 3x3, no LDS
// 1 px/thread, 64x4 tile per 256-thread block, 2048 blocks -> 8 blocks/CU.
// Neighbor loads are coalesced and L1/L2-serviced; weights via scalar cache.
template<int CIN, int COUT, bool RELU>
__global__ __launch_bounds__(256) void conv_direct(const float* __restrict__ in,
    const float* __restrict__ w, const float* __restrict__ bias,
    float* __restrict__ out) {
  const int b = blockIdx.z;
  const int x = blockIdx.x * 64 + (threadIdx.x & 63);
  const int y = blockIdx.y * 4 + (threadIdx.x >> 6);
  const float* inb = in + (size_t)b * CIN * HW;

  float acc[COUT];
  #pragma unroll
  for (int co = 0; co < COUT; ++co) acc[co] = bias[co];

  #pragma unroll
  for (int ci = 0; ci < CIN; ++ci) {
    const float* p = inb + ci * HW + y * WW + x;
    float vv[9];
    #pragma unroll
    for (int dy = -1; dy <= 1; ++dy) {
      #pragma unroll
      for (int dx = -1; dx <= 1; ++dx) {
        bool ok = ((unsigned)(y + dy) < HH) && ((unsigned)(x + dx) < WW);
        vv[(dy + 1) * 3 + (dx + 1)] = ok ? p[dy * WW + dx] : 0.f;
      }
    }
    #pragma unroll
    for (int co = 0; co < COUT; ++co) {
      #pragma unroll
      for (int t = 0; t < 9; ++t)
        acc[co] = fmaf(vv[t], w[(co * CIN + ci) * 9 + t], acc[co]);
    }
  }
  float* outb = out + (size_t)b * COUT * HW;
  const int pix = y * WW + x;
  #pragma unroll
  for (int co = 0; co < COUT; ++co) {
    float r = RELU ? fmaxf(acc[co], 0.f) : acc[co];
    outb[co * HW + pix] = r;
  }
}

// -------------------- final conv (10->5, no relu) + imfeat build (direct style)
// imfeat channels: 0..4 s1, 5..7 X, 8 x*ck, 9 y*ck
__global__ __launch_bounds__(256) void conv_final_direct(const float* __restrict__ in,
    const float* __restrict__ w, const float* __restrict__ bias,
    const float* __restrict__ X, float* __restrict__ imfeat) {
  const int b = blockIdx.z;
  const int x = blockIdx.x * 64 + (threadIdx.x & 63);
  const int y = blockIdx.y * 4 + (threadIdx.x >> 6);
  const float* inb = in + (size_t)b * 10 * HW;

  float acc[5];
  #pragma unroll
  for (int co = 0; co < 5; ++co) acc[co] = bias[co];

  #pragma unroll
  for (int ci = 0; ci < 10; ++ci) {
    const float* p = inb + ci * HW + y * WW + x;
    float vv[9];
    #pragma unroll
    for (int dy = -1; dy <= 1; ++dy) {
      #pragma unroll
      for (int dx = -1; dx <= 1; ++dx) {
        bool ok = ((unsigned)(y + dy) < HH) && ((unsigned)(x + dx) < WW);
        vv[(dy + 1) * 3 + (dx + 1)] = ok ? p[dy * WW + dx] : 0.f;
      }
    }
    #pragma unroll
    for (int co = 0; co < 5; ++co) {
      #pragma unroll
      for (int t = 0; t < 9; ++t)
        acc[co] = fmaf(vv[t], w[(co * 10 + ci) * 9 + t], acc[co]);
    }
  }
  float* ob = imfeat + (size_t)b * 10 * HW;
  const float* Xb = X + (size_t)b * 3 * HW;
  const int pix = y * WW + x;
  #pragma unroll
  for (int co = 0; co < 5; ++co) ob[co * HW + pix] = acc[co];
  #pragma unroll
  for (int c = 0; c < 3; ++c) ob[(5 + c) * HW + pix] = Xb[c * HW + pix];
  ob[8 * HW + pix] = (float)x * CKXY;
  ob[9 * HW + pix] = (float)y * CKXY;
}

// ------------------------------------------------- cent0 = blockmean(imfeat')
__global__ __launch_bounds__(256) void blockmean0(const float* __restrict__ imfeat,
                                                  float* __restrict__ cent) {
  const int cx = blockIdx.x, cy = blockIdx.y, b = blockIdx.z;
  const int tid = threadIdx.x;
  const int col = tid & 31, row0 = tid >> 5;
  float acc[10];
  #pragma unroll
  for (int ch = 0; ch < 10; ++ch) acc[ch] = 0.f;
  for (int p = 0; p < 4; ++p) {
    const int y = cy * 32 + row0 + p * 8;
    const int x = cx * 32 + col;
    #pragma unroll
    for (int ch = 0; ch < 10; ++ch)
      acc[ch] += imfeat[((b * 10 + ch) * HH + y) * WW + x];
  }
  #pragma unroll
  for (int off = 32; off; off >>= 1) {
    #pragma unroll
    for (int ch = 0; ch < 10; ++ch) acc[ch] += __shfl_down(acc[ch], off);
  }
  __shared__ float sPart[4][10];
  const int wave = tid >> 6, lane = tid & 63;
  if (lane == 0) {
    #pragma unroll
    for (int ch = 0; ch < 10; ++ch) sPart[wave][ch] = acc[ch];
  }
  __syncthreads();
  if (tid < 10) {
    float s = sPart[0][tid] + sPart[1][tid] + sPart[2][tid] + sPart[3][tid];
    cent[((b * 10 + tid) * 16 + cy) * 16 + cx] = s * (1.0f / 1024.0f);
  }
}

// -------------------- SSN iteration: (optional in-block centroid) + aff + sums
__global__ __launch_bounds__(256) void iter2(const float* __restrict__ imfeat,
    const float* __restrict__ centIn, const float* __restrict__ numP,
    const float* __restrict__ denP, float* __restrict__ numO,
    float* __restrict__ denO, float* __restrict__ affO) {
  const int cx = blockIdx.x, cy = blockIdx.y, b = blockIdx.z;
  const int tid = threadIdx.x;
  __shared__ float sc[9][10];
  __shared__ float nb[9][11];
  if (centIn) {
    if (tid < 90) {
      int s = tid / 10, ch = tid - s * 10;
      int dr = s / 3 - 1, dc = s % 3 - 1;
      int r = min(max(cy + dr, 0), 15), c = min(max(cx + dc, 0), 15);
      sc[s][ch] = centIn[((b * 10 + ch) * 16 + r) * 16 + c];
    }
    __syncthreads();
  } else {
    if (tid < 99) {
      int s = tid / 11, j = tid - s * 11;
      int dr = s / 3 - 1, dc = s % 3 - 1;
      int r = min(max(cy + dr, 0), 15), c = min(max(cx + dc, 0), 15);
      float a = 0.f;
      #pragma unroll
      for (int rr = -1; rr <= 1; ++rr)
        #pragma unroll
        for (int cc = -1; cc <= 1; ++cc) {
          int R = r + rr, C = c + cc;
          if ((unsigned)R < 16u && (unsigned)C < 16u)
            a += (j < 10) ? numP[((b * 10 + j) * 16 + R) * 16 + C]
                          : denP[(b * 16 + R) * 16 + C];
        }
      nb[s][j] = a;
    }
    __syncthreads();
    if (tid < 90) {
      int s = tid / 10, ch = tid - s * 10;
      sc[s][ch] = nb[s][ch] / nb[s][10];
    }
    __syncthreads();
  }

  float accN[10];
  #pragma unroll
  for (int ch = 0; ch < 10; ++ch) accN[ch] = 0.f;
  float accD = 0.f;
  const int col = tid & 31, row0 = tid >> 5;
  for (int p = 0; p < 4; ++p) {
    const int y = cy * 32 + row0 + p * 8;
    const int x = cx * 32 + col;
    float f[10];
    #pragma unroll
    for (int ch = 0; ch < 10; ++ch)
      f[ch] = imfeat[((b * 10 + ch) * HH + y) * WW + x];
    float asum = 0.f;
    #pragma unroll
    for (int s = 0; s < 9; ++s) {
      float ss = 0.f;
      #pragma unroll
      for (int ch = 0; ch < 10; ++ch) { float d = f[ch] - sc[s][ch]; ss = fmaf(d, d, ss); }
      float a = __expf(-ss * (1.0f / 1000.0f));
      asum += a;
      if (affO) affO[((b * 9 + s) * HH + y) * WW + x] = a;
    }
    accD += asum;
    #pragma unroll
    for (int ch = 0; ch < 10; ++ch) accN[ch] = fmaf(f[ch], asum, accN[ch]);
  }
  #pragma unroll
  for (int off = 32; off; off >>= 1) {
    accD += __shfl_down(accD, off);
    #pragma unroll
    for (int ch = 0; ch < 10; ++ch) accN[ch] += __shfl_down(accN[ch], off);
  }
  __shared__ float sPart[4][11];
  const int wave = tid >> 6, lane = tid & 63;
  if (lane == 0) {
    #pragma unroll
    for (int ch = 0; ch < 10; ++ch) sPart[wave][ch] = accN[ch];
    sPart[wave][10] = accD;
  }
  __syncthreads();
  if (tid < 11) {
    float s = sPart[0][tid] + sPart[1][tid] + sPart[2][tid] + sPart[3][tid];
    if (tid < 10) numO[((b * 10 + tid) * 16 + cy) * 16 + cx] = s;
    else denO[(b * 16 + cy) * 16 + cx] = s;
  }
}

// ------------------------------- final cent = box3(num)/box3(den) -> output
__global__ __launch_bounds__(256) void cent_final(const float* __restrict__ num_bs,
    const float* __restrict__ den_bs, float* __restrict__ out_cent) {
  const int b = blockIdx.x;
  const int tid = threadIdx.x;
  const int cy = tid >> 4, cx = tid & 15;
  float den = 0.f;
  #pragma unroll
  for (int dr = -1; dr <= 1; ++dr)
    #pragma unroll
    for (int dc = -1; dc <= 1; ++dc) {
      int r = cy + dr, c = cx + dc;
      if ((unsigned)r < 16 && (unsigned)c < 16) den += den_bs[(b * 16 + r) * 16 + c];
    }
  #pragma unroll
  for (int ch = 0; ch < 10; ++ch) {
    float num = 0.f;
    #pragma unroll
    for (int dr = -1; dr <= 1; ++dr)
      #pragma unroll
      for (int dc = -1; dc <= 1; ++dc) {
        int r = cy + dr, c = cx + dc;
        if ((unsigned)r < 16 && (unsigned)c < 16)
          num += num_bs[((b * 10 + ch) * 16 + r) * 16 + c];
      }
    float invck = (ch >= 8) ? (1.0f / CKXY) : 1.0f;
    out_cent[((b * 10 + ch) * 16 + cy) * 16 + cx] = (num / den) * invck;
  }
}

// ---------------------------------------------------------------------------
extern "C" void kernel_launch(void* const* d_in, const int* in_sizes, int n_in,
                              void* d_out, int out_size, void* d_ws, size_t ws_size,
                              hipStream_t stream) {
  const float* X      = (const float*)d_in[0];
  const float* w0     = (const float*)d_in[1];
  const float* b0     = (const float*)d_in[2];
  const float* ws_mid = (const float*)d_in[3];
  const float* bs_mid = (const float*)d_in[4];
  const float* wf     = (const float*)d_in[5];
  const float* bf     = (const float*)d_in[6];
  float* out = (float*)d_out;

  const size_t plane = (size_t)BB * 10 * HW;  // 5,242,880 floats
  float* bufA  = (float*)d_ws;
  float* bufB  = bufA + plane;
  float* num0  = bufB + plane;
  float* den0  = num0 + BB * 10 * 256;
  float* num1  = den0 + BB * 256;
  float* den1  = num1 + BB * 10 * 256;
  float* centA = den1 + BB * 256;

  dim3 dgrid(8, 128, BB);   // 64x4 tiles, 2048 blocks
  conv_direct<3, 10, true><<<dgrid, 256, 0, stream>>>(X, w0, b0, bufA);
  const float* cur = bufA;
  float* nxt = bufB;
  for (int l = 0; l < 8; ++l) {
    conv_direct<10, 10, true><<<dgrid, 256, 0, stream>>>(cur, ws_mid + l * 900, bs_mid + l * 10, nxt);
    const float* t = cur; cur = nxt; nxt = (float*)t;
  }
  // cur == bufA after 8 swaps; imfeat -> bufB
  conv_final_direct<<<dgrid, 256, 0, stream>>>(cur, wf, bf, X, bufB);

  dim3 igrid(16, 16, BB);
  blockmean0<<<igrid, 256, 0, stream>>>(bufB, centA);

  float* aff_out = out + BB * 10 * 256;  // cent (5120) then aff
  float* nums[2] = {num0, num1};
  float* dens[2] = {den0, den1};
  for (int k = 0; k < 10; ++k) {
    iter2<<<igrid, 256, 0, stream>>>(bufB,
        (k == 0) ? centA : nullptr,
        (k == 0) ? nullptr : nums[(k - 1) & 1],
        (k == 0) ? nullptr : dens[(k - 1) & 1],
        nums[k & 1], dens[k & 1],
        (k == 9) ? aff_out : nullptr);
  }
  cent_final<<<dim3(BB), 256, 0, stream>>>(nums[1], dens[1], out);
}

// Round 7
// 487.808 us; speedup vs baseline: 1.1699x; 1.1699x over previous
//
#include <hip/hip_runtime.h>

#define HH 512
#define WW 512
#define BB 2
#define CKXY 0.3125f   /* COMPACT / sqrt(H*W/NSUP) = 10/32 */
#define HW (HH*WW)

// ---------------- conv 3x3: 16x16 tile, 1 px/thread, channel-group dbuf LDS
// LDS [2 buf][2 ch][18 rows][stride 40] = 11.5 KB -> 8 blocks/CU (32 waves).
// Stage group g+1 overlaps compute of group g; one barrier per 2-channel group.
template<int CIN, int COUT, bool RELU>
__global__ __launch_bounds__(256) void conv_cg(const float* __restrict__ in,
    const float* __restrict__ w, const float* __restrict__ bias,
    float* __restrict__ out) {
  constexpr int NG = (CIN + 1) / 2;
  const int bx = blockIdx.x, by = blockIdx.y, b = blockIdx.z;
  const int tid = threadIdx.x;
  const int tx = tid & 15, ty = tid >> 4;
  const int gy0 = by * 16, gx0 = bx * 16;
  __shared__ float sIn[2][2][18][40];
  const float* inb = in + (size_t)b * CIN * HW;

  auto stage = [&](int g, int buf) {
    const int nch = (CIN - g * 2) >= 2 ? 2 : 1;
    // interior 16x16: one coalesced load per thread per channel
    #pragma unroll
    for (int cg = 0; cg < 2; ++cg) {
      if (cg < nch)
        sIn[buf][cg][ty + 1][tx + 1] =
            inb[(g * 2 + cg) * HW + (gy0 + ty) * WW + gx0 + tx];
    }
    // halo ring: 68 elems/channel
    if (tid < nch * 68) {
      int cg = tid / 68, rem = tid - cg * 68;
      int ly, lx;
      if (rem < 18)      { ly = 0;  lx = rem; }
      else if (rem < 36) { ly = 17; lx = rem - 18; }
      else if (rem < 52) { lx = 0;  ly = rem - 36 + 1; }
      else               { lx = 17; ly = rem - 52 + 1; }
      int gy = gy0 + ly - 1, gx = gx0 + lx - 1;
      float v = 0.f;
      if ((unsigned)gy < HH && (unsigned)gx < WW)
        v = inb[(g * 2 + cg) * HW + gy * WW + gx];
      sIn[buf][cg][ly][lx] = v;
    }
  };

  float acc[COUT];
  #pragma unroll
  for (int co = 0; co < COUT; ++co) acc[co] = bias[co];

  stage(0, 0);
  __syncthreads();
  for (int g = 0; g < NG; ++g) {
    if (g + 1 < NG) stage(g + 1, (g + 1) & 1);
    const int nch = (CIN - g * 2) >= 2 ? 2 : 1;
    const int buf = g & 1;
    for (int cg = 0; cg < nch; ++cg) {
      const int ci = g * 2 + cg;
      float v[9];
      #pragma unroll
      for (int t = 0; t < 9; ++t) v[t] = sIn[buf][cg][ty + t / 3][tx + t % 3];
      #pragma unroll
      for (int co = 0; co < COUT; ++co) {
        #pragma unroll
        for (int t = 0; t < 9; ++t)
          acc[co] = fmaf(v[t], w[(co * CIN + ci) * 9 + t], acc[co]);
      }
    }
    __syncthreads();
  }

  float* outb = out + (size_t)b * COUT * HW;
  const int pix = (gy0 + ty) * WW + gx0 + tx;
  #pragma unroll
  for (int co = 0; co < COUT; ++co) {
    float r = RELU ? fmaxf(acc[co], 0.f) : acc[co];
    outb[co * HW + pix] = r;
  }
}

// ---------------- final conv (10->5) + imfeat build, same dbuf structure
// imfeat channels: 0..4 s1, 5..7 X, 8 x*ck, 9 y*ck
__global__ __launch_bounds__(256) void conv_final_cg(const float* __restrict__ in,
    const float* __restrict__ w, const float* __restrict__ bias,
    const float* __restrict__ X, float* __restrict__ imfeat) {
  const int bx = blockIdx.x, by = blockIdx.y, b = blockIdx.z;
  const int tid = threadIdx.x;
  const int tx = tid & 15, ty = tid >> 4;
  const int gy0 = by * 16, gx0 = bx * 16;
  __shared__ float sIn[2][2][18][40];
  const float* inb = in + (size_t)b * 10 * HW;

  auto stage = [&](int g, int buf) {
    #pragma unroll
    for (int cg = 0; cg < 2; ++cg)
      sIn[buf][cg][ty + 1][tx + 1] =
          inb[(g * 2 + cg) * HW + (gy0 + ty) * WW + gx0 + tx];
    if (tid < 136) {
      int cg = tid / 68, rem = tid - cg * 68;
      int ly, lx;
      if (rem < 18)      { ly = 0;  lx = rem; }
      else if (rem < 36) { ly = 17; lx = rem - 18; }
      else if (rem < 52) { lx = 0;  ly = rem - 36 + 1; }
      else               { lx = 17; ly = rem - 52 + 1; }
      int gy = gy0 + ly - 1, gx = gx0 + lx - 1;
      float v = 0.f;
      if ((unsigned)gy < HH && (unsigned)gx < WW)
        v = inb[(g * 2 + cg) * HW + gy * WW + gx];
      sIn[buf][cg][ly][lx] = v;
    }
  };

  float acc[5];
  #pragma unroll
  for (int co = 0; co < 5; ++co) acc[co] = bias[co];

  stage(0, 0);
  __syncthreads();
  for (int g = 0; g < 5; ++g) {
    if (g + 1 < 5) stage(g + 1, (g + 1) & 1);
    const int buf = g & 1;
    #pragma unroll
    for (int cg = 0; cg < 2; ++cg) {
      const int ci = g * 2 + cg;
      float v[9];
      #pragma unroll
      for (int t = 0; t < 9; ++t) v[t] = sIn[buf][cg][ty + t / 3][tx + t % 3];
      #pragma unroll
      for (int co = 0; co < 5; ++co) {
        #pragma unroll
        for (int t = 0; t < 9; ++t)
          acc[co] = fmaf(v[t], w[(co * 10 + ci) * 9 + t], acc[co]);
      }
    }
    __syncthreads();
  }

  float* ob = imfeat + (size_t)b * 10 * HW;
  const float* Xb = X + (size_t)b * 3 * HW;
  const int x = gx0 + tx, y = gy0 + ty;
  const int pix = y * WW + x;
  #pragma unroll
  for (int co = 0; co < 5; ++co) ob[co * HW + pix] = acc[co];
  #pragma unroll
  for (int c = 0; c < 3; ++c) ob[(5 + c) * HW + pix] = Xb[c * HW + pix];
  ob[8 * HW + pix] = (float)x * CKXY;
  ob[9 * HW + pix] = (float)y * CKXY;
}

// ------------------------------------------------- cent0 = blockmean(imfeat')
__global__ __launch_bounds__(256) void blockmean0(const float* __restrict__ imfeat,
                                                  float* __restrict__ cent) {
  const int cx = blockIdx.x, cy = blockIdx.y, b = blockIdx.z;
  const int tid = threadIdx.x;
  const int col = tid & 31, row0 = tid >> 5;
  float acc[10];
  #pragma unroll
  for (int ch = 0; ch < 10; ++ch) acc[ch] = 0.f;
  for (int p = 0; p < 4; ++p) {
    const int y = cy * 32 + row0 + p * 8;
    const int x = cx * 32 + col;
    #pragma unroll
    for (int ch = 0; ch < 10; ++ch)
      acc[ch] += imfeat[((b * 10 + ch) * HH + y) * WW + x];
  }
  #pragma unroll
  for (int off = 32; off; off >>= 1) {
    #pragma unroll
    for (int ch = 0; ch < 10; ++ch) acc[ch] += __shfl_down(acc[ch], off);
  }
  __shared__ float sPart[4][10];
  const int wave = tid >> 6, lane = tid & 63;
  if (lane == 0) {
    #pragma unroll
    for (int ch = 0; ch < 10; ++ch) sPart[wave][ch] = acc[ch];
  }
  __syncthreads();
  if (tid < 10) {
    float s = sPart[0][tid] + sPart[1][tid] + sPart[2][tid] + sPart[3][tid];
    cent[((b * 10 + tid) * 16 + cy) * 16 + cx] = s * (1.0f / 1024.0f);
  }
}

// -------------------- SSN iteration: (optional in-block centroid) + aff + sums
__global__ __launch_bounds__(256) void iter2(const float* __restrict__ imfeat,
    const float* __restrict__ centIn, const float* __restrict__ numP,
    const float* __restrict__ denP, float* __restrict__ numO,
    float* __restrict__ denO, float* __restrict__ affO) {
  const int cx = blockIdx.x, cy = blockIdx.y, b = blockIdx.z;
  const int tid = threadIdx.x;
  __shared__ float sc[9][10];
  __shared__ float nb[9][11];
  if (centIn) {
    if (tid < 90) {
      int s = tid / 10, ch = tid - s * 10;
      int dr = s / 3 - 1, dc = s % 3 - 1;
      int r = min(max(cy + dr, 0), 15), c = min(max(cx + dc, 0), 15);
      sc[s][ch] = centIn[((b * 10 + ch) * 16 + r) * 16 + c];
    }
    __syncthreads();
  } else {
    if (tid < 99) {
      int s = tid / 11, j = tid - s * 11;
      int dr = s / 3 - 1, dc = s % 3 - 1;
      int r = min(max(cy + dr, 0), 15), c = min(max(cx + dc, 0), 15);
      float a = 0.f;
      #pragma unroll
      for (int rr = -1; rr <= 1; ++rr)
        #pragma unroll
        for (int cc = -1; cc <= 1; ++cc) {
          int R = r + rr, C = c + cc;
          if ((unsigned)R < 16u && (unsigned)C < 16u)
            a += (j < 10) ? numP[((b * 10 + j) * 16 + R) * 16 + C]
                          : denP[(b * 16 + R) * 16 + C];
        }
      nb[s][j] = a;
    }
    __syncthreads();
    if (tid < 90) {
      int s = tid / 10, ch = tid - s * 10;
      sc[s][ch] = nb[s][ch] / nb[s][10];
    }
    __syncthreads();
  }

  float accN[10];
  #pragma unroll
  for (int ch = 0; ch < 10; ++ch) accN[ch] = 0.f;
  float accD = 0.f;
  const int col = tid & 31, row0 = tid >> 5;
  for (int p = 0; p < 4; ++p) {
    const int y = cy * 32 + row0 + p * 8;
    const int x = cx * 32 + col;
    float f[10];
    #pragma unroll
    for (int ch = 0; ch < 10; ++ch)
      f[ch] = imfeat[((b * 10 + ch) * HH + y) * WW + x];
    float asum = 0.f;
    #pragma unroll
    for (int s = 0; s < 9; ++s) {
      float ss = 0.f;
      #pragma unroll
      for (int ch = 0; ch < 10; ++ch) { float d = f[ch] - sc[s][ch]; ss = fmaf(d, d, ss); }
      float a = __expf(-ss * (1.0f / 1000.0f));
      asum += a;
      if (affO) affO[((b * 9 + s) * HH + y) * WW + x] = a;
    }
    accD += asum;
    #pragma unroll
    for (int ch = 0; ch < 10; ++ch) accN[ch] = fmaf(f[ch], asum, accN[ch]);
  }
  #pragma unroll
  for (int off = 32; off; off >>= 1) {
    accD += __shfl_down(accD, off);
    #pragma unroll
    for (int ch = 0; ch < 10; ++ch) accN[ch] += __shfl_down(accN[ch], off);
  }
  __shared__ float sPart[4][11];
  const int wave = tid >> 6, lane = tid & 63;
  if (lane == 0) {
    #pragma unroll
    for (int ch = 0; ch < 10; ++ch) sPart[wave][ch] = accN[ch];
    sPart[wave][10] = accD;
  }
  __syncthreads();
  if (tid < 11) {
    float s = sPart[0][tid] + sPart[1][tid] + sPart[2][tid] + sPart[3][tid];
    if (tid < 10) numO[((b * 10 + tid) * 16 + cy) * 16 + cx] = s;
    else denO[(b * 16 + cy) * 16 + cx] = s;
  }
}

// ------------------------------- final cent = box3(num)/box3(den) -> output
__global__ __launch_bounds__(256) void cent_final(const float* __restrict__ num_bs,
    const float* __restrict__ den_bs, float* __restrict__ out_cent) {
  const int b = blockIdx.x;
  const int tid = threadIdx.x;
  const int cy = tid >> 4, cx = tid & 15;
  float den = 0.f;
  #pragma unroll
  for (int dr = -1; dr <= 1; ++dr)
    #pragma unroll
    for (int dc = -1; dc <= 1; ++dc) {
      int r = cy + dr, c = cx + dc;
      if ((unsigned)r < 16 && (unsigned)c < 16) den += den_bs[(b * 16 + r) * 16 + c];
    }
  #pragma unroll
  for (int ch = 0; ch < 10; ++ch) {
    float num = 0.f;
    #pragma unroll
    for (int dr = -1; dr <= 1; ++dr)
      #pragma unroll
      for (int dc = -1; dc <= 1; ++dc) {
        int r = cy + dr, c = cx + dc;
        if ((unsigned)r < 16 && (unsigned)c < 16)
          num += num_bs[((b * 10 + ch) * 16 + r) * 16 + c];
      }
    float invck = (ch >= 8) ? (1.0f / CKXY) : 1.0f;
    out_cent[((b * 10 + ch) * 16 + cy) * 16 + cx] = (num / den) * invck;
  }
}

// ---------------------------------------------------------------------------
extern "C" void kernel_launch(void* const* d_in, const int* in_sizes, int n_in,
                              void* d_out, int out_size, void* d_ws, size_t ws_size,
                              hipStream_t stream) {
  const float* X      = (const float*)d_in[0];
  const float* w0     = (const float*)d_in[1];
  const float* b0     = (const float*)d_in[2];
  const float* ws_mid = (const float*)d_in[3];
  const float* bs_mid = (const float*)d_in[4];
  const float* wf     = (const float*)d_in[5];
  const float* bf     = (const float*)d_in[6];
  float* out = (float*)d_out;

  const size_t plane = (size_t)BB * 10 * HW;  // 5,242,880 floats
  float* bufA  = (float*)d_ws;
  float* bufB  = bufA + plane;
  float* num0  = bufB + plane;
  float* den0  = num0 + BB * 10 * 256;
  float* num1  = den0 + BB * 256;
  float* den1  = num1 + BB * 10 * 256;
  float* centA = den1 + BB * 256;

  dim3 cgrid(32, 32, BB);   // 16x16 tiles, 2048 blocks
  conv_cg<3, 10, true><<<cgrid, 256, 0, stream>>>(X, w0, b0, bufA);
  const float* cur = bufA;
  float* nxt = bufB;
  for (int l = 0; l < 8; ++l) {
    conv_cg<10, 10, true><<<cgrid, 256, 0, stream>>>(cur, ws_mid + l * 900, bs_mid + l * 10, nxt);
    const float* t = cur; cur = nxt; nxt = (float*)t;
  }
  // cur == bufA after 8 swaps; imfeat -> bufB
  conv_final_cg<<<cgrid, 256, 0, stream>>>(cur, wf, bf, X, bufB);

  dim3 igrid(16, 16, BB);
  blockmean0<<<igrid, 256, 0, stream>>>(bufB, centA);

  float* aff_out = out + BB * 10 * 256;  // cent (5120) then aff
  float* nums[2] = {num0, num1};
  float* dens[2] = {den0, den1};
  for (int k = 0; k < 10; ++k) {
    iter2<<<igrid, 256, 0, stream>>>(bufB,
        (k == 0) ? centA : nullptr,
        (k == 0) ? nullptr : nums[(k - 1) & 1],
        (k == 0) ? nullptr : dens[(k - 1) & 1],
        nums[k & 1], dens[k & 1],
        (k == 9) ? aff_out : nullptr);
  }
  cent_final<<<dim3(BB), 256, 0, stream>>>(nums[1], dens[1], out);
}